// Round 13
// baseline (47.418 us; speedup 1.0000x reference)
//
#include <hip/hip_runtime.h>
#include <math.h>

#define NDET 16
#define NDIM 16

// ---- quad (4-lane) DPP broadcast: pure VALU, no LDS path -----------------
template<int OWNER>
__device__ __forceinline__ float bcast4f(float v) {
    constexpr int ctrl = OWNER * 0x55;  // quad_perm:[OWNER]*4
    return __int_as_float(
        __builtin_amdgcn_mov_dpp(__float_as_int(v), ctrl, 0xF, 0xF, true));
}

// ---- Householder QR step, COLUMN-INVOLUTION ORDER (R11-verbatim math) -----
// Step K eliminates global column perm(K) = ((K&3)<<2)|(K>>2): involution,
// 6 transpositions -> det(P)=+1. Owner lane = K&3, local col = K>>2, and
// local cols j < K>>2 are retired on EVERY lane -> uniform shrinking j-loop.
template<int K>
__device__ __forceinline__ void qr_step(float (&c)[4][16], float &prod, float &sgn) {
    constexpr int OWNER = K & 3;
    constexpr int LC    = K >> 2;
    constexpr int JMIN  = K >> 2;

    float s0 = 0.0f, s1 = 0.0f;
    #pragma unroll
    for (int i = K; i < 16; i += 2)     s0 = fmaf(c[LC][i], c[LC][i], s0);
    #pragma unroll
    for (int i = K + 1; i < 16; i += 2) s1 = fmaf(c[LC][i], c[LC][i], s1);

    const float n2    = bcast4f<OWNER>(s0 + s1);
    const float xK    = bcast4f<OWNER>(c[LC][K]);
    const float alpha = __builtin_amdgcn_sqrtf(n2);          // ||x|| > 0 a.s.
    const float vK    = xK + copysignf(alpha, xK);           // |vK| = alpha + |xK|
    const float beta  = __builtin_amdgcn_rcpf(alpha * fabsf(vK));
    prod *= alpha;
    sgn = (xK < 0.0f) ? -sgn : sgn;

    float bv[16];                       // const-indexed -> registers
    bv[K] = vK;
    #pragma unroll
    for (int i = K + 1; i < 16; ++i) bv[i] = bcast4f<OWNER>(c[LC][i]);

    #pragma unroll
    for (int j = JMIN; j < 4; ++j) {
        float w0 = bv[K] * c[j][K], w1 = 0.0f;
        #pragma unroll
        for (int i = K + 1; i < 16; i += 2) w0 = fmaf(bv[i], c[j][i], w0);
        #pragma unroll
        for (int i = K + 2; i < 16; i += 2) w1 = fmaf(bv[i], c[j][i], w1);
        const float t = (w0 + w1) * beta;
        #pragma unroll
        for (int i = K; i < 16; ++i)
            c[j][i] = fmaf(-t, bv[i], c[j][i]);
    }
}

template<int K>
__device__ __forceinline__ void qr_all(float (&c)[4][16], float &prod, float &sgn) {
    qr_step<K>(c, prod, sgn);
    if constexpr (K < 14) qr_all<K + 1>(c, prod, sgn);
}

// LANE SPECIALIZATION: quad 2g handles matrix A of det g, quad 2g+1 handles
// matrix B. One SIMT instruction stream factorizes both simultaneously
// (quad_perm DPP is quad-local), so per-wave instructions HALVE and VGPR
// stays at single-matrix level -> 2x TLP with no ILP register cost.
// 256 threads = 64 quads = 32 (det,half) pairs... = 32 dets = 2 samples.
__global__ __launch_bounds__(256) void logabssumdet_kernel(
    const float* __restrict__ a,
    const float* __restrict__ b,
    const float* __restrict__ w,
    float* __restrict__ out,
    int n_samples)
{
    const int tid    = threadIdx.x;
    const int lane4  = tid & 3;
    const int quad   = tid >> 2;                    // 0..63 in block
    const int half   = quad & 1;                    // 0 -> A, 1 -> B
    const int det_l  = quad >> 1;                   // 0..31 local det index
    const int mat_id = blockIdx.x * 32 + det_l;     // = sample*16 + det
    const int n_mats = n_samples * NDET;

    __shared__ float sx[64];    // per-quad: log|det(half)|
    __shared__ float ss[64];    // per-quad: sign(half)

    float x = 0.0f, sgn = 1.0f;

    if (mat_id < n_mats) {
        const float* src = half ? b : a;
        const float4* mb =
            reinterpret_cast<const float4*>(src + (size_t)mat_id * (NDIM * NDIM)) + lane4;

        float c[4][16];
        #pragma unroll
        for (int i = 0; i < 16; ++i) {
            const float4 v = mb[i * 4];             // 64B contiguous per quad
            c[0][i] = v.x; c[1][i] = v.y; c[2][i] = v.z; c[3][i] = v.w;
        }

        float prod = 1.0f;                          // product of alpha_K (>0)
        qr_all<0>(c, prod, sgn);                    // 15 reflections
        prod *= bcast4f<3>(c[3][15]);               // column perm(15)=15 remainder

        x = __logf(fabsf(prod));                    // f32-range safe (R11-proven)
        sgn = (prod < 0.0f) ? -sgn : sgn;
    }

    if (lane4 == 0) { sx[quad] = x; ss[quad] = sgn; }
    __syncthreads();

    // 2 samples per block; one thread finishes each sample's 16-det LSE
    if (tid < 2) {
        const int sample = blockIdx.x * 2 + tid;
        if (sample < n_samples) {
            const int base = tid * 2 * NDET;        // 32 quad entries per sample
            float xs[NDET];
            float gs[NDET];
            float xmax = -INFINITY;
            #pragma unroll
            for (int d = 0; d < NDET; ++d) {
                xs[d] = sx[base + 2 * d] + sx[base + 2 * d + 1];
                gs[d] = ss[base + 2 * d] * ss[base + 2 * d + 1];
                xmax  = fmaxf(xmax, xs[d]);
            }
            float sum = 0.0f;
            #pragma unroll
            for (int d = 0; d < NDET; ++d)
                sum += gs[d] * __expf(xs[d] - xmax) * w[d];
            out[sample] = __logf(fabsf(sum)) + xmax;
            out[n_samples + sample] = (sum > 0.0f) ? 1.0f : ((sum < 0.0f) ? -1.0f : 0.0f);
        }
    }
}

extern "C" void kernel_launch(void* const* d_in, const int* in_sizes, int n_in,
                              void* d_out, int out_size, void* d_ws, size_t ws_size,
                              hipStream_t stream)
{
    const float* a = (const float*)d_in[0];
    const float* b = (const float*)d_in[1];
    const float* w = (const float*)d_in[2];
    float* out = (float*)d_out;

    const int n_samples = in_sizes[0] / (NDET * NDIM * NDIM);
    const int blocks = (n_samples + 1) / 2;   // 2 samples (64 matrices) per block
    logabssumdet_kernel<<<blocks, 256, 0, stream>>>(a, b, w, out, n_samples);
}

// Round 14
// 47.131 us; speedup vs baseline: 1.0061x; 1.0061x over previous
//
#include <hip/hip_runtime.h>
#include <math.h>

#define NDET 16
#define NDIM 16

typedef float v2f __attribute__((ext_vector_type(2)));

// ---- quad (4-lane) DPP broadcast: pure VALU, no LDS path -----------------
template<int OWNER>
__device__ __forceinline__ float bcast4f(float v) {
    constexpr int ctrl = OWNER * 0x55;  // quad_perm:[OWNER]*4
    return __int_as_float(
        __builtin_amdgcn_mov_dpp(__float_as_int(v), ctrl, 0xF, 0xF, true));
}

// ---- Householder QR step, involution order, ROW-PAIR PACKED ---------------
// Same math as R11/R13 (proven absmax 0.125): step K eliminates global column
// perm(K)=((K&3)<<2)|(K>>2); owner lane = K&3, local col = K>>2, retired local
// cols j < K>>2 on every lane. Matrix stored as v2f cp[4][8] (row pairs) so
// dot/update/norm use v_pk_fma_f32 (2 FMA per instruction) -> ~35% fewer
// VALU instructions. Odd-K row masking: zero bv[K-1] inside its pair.
template<int K>
__device__ __forceinline__ void qr_step(v2f (&cp)[4][8], float &prod, float &sgn) {
    constexpr int OWNER = K & 3;        // lane owning column perm(K)
    constexpr int LC    = K >> 2;       // its local column index
    constexpr int JMIN  = K >> 2;       // first possibly-active local column
    constexpr int RP    = K >> 1;       // pair containing row K
    constexpr int R0    = (K + 1) >> 1; // first fully-active pair

    // ---- ||x||^2 over rows K..15 of local column LC (packed + odd fixup)
    v2f nacc = {0.0f, 0.0f};
    #pragma unroll
    for (int r = R0; r < 8; ++r)
        nacc = __builtin_elementwise_fma(cp[LC][r], cp[LC][r], nacc);
    float nsum = nacc.x + nacc.y;
    if constexpr (K & 1) {
        const float e = cp[LC][RP].y;   // row K sits in .y of straddling pair
        nsum = fmaf(e, e, nsum);
    }

    float xKl;
    if constexpr (K & 1) xKl = cp[LC][RP].y; else xKl = cp[LC][RP].x;

    const float n2    = bcast4f<OWNER>(nsum);
    const float xK    = bcast4f<OWNER>(xKl);
    const float alpha = __builtin_amdgcn_sqrtf(n2);          // ||x|| > 0 a.s.
    const float vK    = xK + copysignf(alpha, xK);           // |vK| = alpha+|xK|
    const float beta  = __builtin_amdgcn_rcpf(alpha * fabsf(vK));
    prod *= alpha;
    sgn = (xK < 0.0f) ? -sgn : sgn;

    // ---- packed reflector bvp[RP..7]; row < K zeroed within pair RP
    v2f bvp[8];
    if constexpr (K & 1) {
        bvp[RP].x = 0.0f;               // row K-1 masked out
        bvp[RP].y = vK;                 // row K
    } else {
        bvp[RP].x = vK;                              // row K
        bvp[RP].y = bcast4f<OWNER>(cp[LC][RP].y);    // row K+1
    }
    #pragma unroll
    for (int r = RP + 1; r < 8; ++r) {
        bvp[r].x = bcast4f<OWNER>(cp[LC][r].x);
        bvp[r].y = bcast4f<OWNER>(cp[LC][r].y);
    }

    // ---- apply H to local columns JMIN..3 (packed dot + packed update)
    #pragma unroll
    for (int j = JMIN; j < 4; ++j) {
        v2f wacc = {0.0f, 0.0f};
        #pragma unroll
        for (int r = RP; r < 8; ++r)
            wacc = __builtin_elementwise_fma(bvp[r], cp[j][r], wacc);
        const float t = (wacc.x + wacc.y) * beta;
        const v2f nt = {-t, -t};
        #pragma unroll
        for (int r = RP; r < 8; ++r)
            cp[j][r] = __builtin_elementwise_fma(nt, bvp[r], cp[j][r]);
    }
}

template<int K>
__device__ __forceinline__ void qr_all(v2f (&cp)[4][8], float &prod, float &sgn) {
    qr_step<K>(cp, prod, sgn);
    if constexpr (K < 14) qr_all<K + 1>(cp, prod, sgn);
}

// LANE SPECIALIZATION (R13 shell): quad 2g -> matrix A of det g, quad 2g+1 ->
// matrix B. One SIMT stream factorizes both; per-wave chains halve.
__global__ __launch_bounds__(256) void logabssumdet_kernel(
    const float* __restrict__ a,
    const float* __restrict__ b,
    const float* __restrict__ w,
    float* __restrict__ out,
    int n_samples)
{
    const int tid    = threadIdx.x;
    const int lane4  = tid & 3;
    const int quad   = tid >> 2;                    // 0..63 in block
    const int half   = quad & 1;                    // 0 -> A, 1 -> B
    const int det_l  = quad >> 1;                   // 0..31 local det index
    const int mat_id = blockIdx.x * 32 + det_l;     // = sample*16 + det
    const int n_mats = n_samples * NDET;

    __shared__ float sx[64];    // per-quad: log|det(half)|
    __shared__ float ss[64];    // per-quad: sign(half)

    float x = 0.0f, sgn = 1.0f;

    if (mat_id < n_mats) {
        const float* src = half ? b : a;
        const float4* mb =
            reinterpret_cast<const float4*>(src + (size_t)mat_id * (NDIM * NDIM)) + lane4;

        v2f cp[4][8];                               // [local col][row pair]
        #pragma unroll
        for (int i = 0; i < 16; ++i) {
            const float4 v = mb[i * 4];             // 64B contiguous per quad
            if ((i & 1) == 0) {
                cp[0][i >> 1].x = v.x; cp[1][i >> 1].x = v.y;
                cp[2][i >> 1].x = v.z; cp[3][i >> 1].x = v.w;
            } else {
                cp[0][i >> 1].y = v.x; cp[1][i >> 1].y = v.y;
                cp[2][i >> 1].y = v.z; cp[3][i >> 1].y = v.w;
            }
        }

        float prod = 1.0f;                          // product of alpha_K (>0)
        qr_all<0>(cp, prod, sgn);                   // 15 reflections
        prod *= bcast4f<3>(cp[3][7].y);             // column perm(15)=15, row 15

        x = __logf(fabsf(prod));                    // f32-range safe (proven)
        sgn = (prod < 0.0f) ? -sgn : sgn;
    }

    if (lane4 == 0) { sx[quad] = x; ss[quad] = sgn; }
    __syncthreads();

    // 2 samples per block; one thread finishes each sample's 16-det LSE
    if (tid < 2) {
        const int sample = blockIdx.x * 2 + tid;
        if (sample < n_samples) {
            const int base = tid * 2 * NDET;        // 32 quad entries per sample
            float xs[NDET];
            float gs[NDET];
            float xmax = -INFINITY;
            #pragma unroll
            for (int d = 0; d < NDET; ++d) {
                xs[d] = sx[base + 2 * d] + sx[base + 2 * d + 1];
                gs[d] = ss[base + 2 * d] * ss[base + 2 * d + 1];
                xmax  = fmaxf(xmax, xs[d]);
            }
            float sum = 0.0f;
            #pragma unroll
            for (int d = 0; d < NDET; ++d)
                sum += gs[d] * __expf(xs[d] - xmax) * w[d];
            out[sample] = __logf(fabsf(sum)) + xmax;
            out[n_samples + sample] = (sum > 0.0f) ? 1.0f : ((sum < 0.0f) ? -1.0f : 0.0f);
        }
    }
}

extern "C" void kernel_launch(void* const* d_in, const int* in_sizes, int n_in,
                              void* d_out, int out_size, void* d_ws, size_t ws_size,
                              hipStream_t stream)
{
    const float* a = (const float*)d_in[0];
    const float* b = (const float*)d_in[1];
    const float* w = (const float*)d_in[2];
    float* out = (float*)d_out;

    const int n_samples = in_sizes[0] / (NDET * NDIM * NDIM);
    const int blocks = (n_samples + 1) / 2;   // 2 samples (64 matrices) per block
    logabssumdet_kernel<<<blocks, 256, 0, stream>>>(a, b, w, out, n_samples);
}